// Round 4
// baseline (652.200 us; speedup 1.0000x reference)
//
#include <hip/hip_runtime.h>

typedef __attribute__((ext_vector_type(8))) short short8;
typedef __attribute__((ext_vector_type(4))) float floatx4;
typedef __attribute__((ext_vector_type(2))) float float2v;
typedef __attribute__((ext_vector_type(4))) unsigned int uint4v;
typedef __attribute__((ext_vector_type(4))) int int4v;
typedef __attribute__((ext_vector_type(2))) unsigned int uint2v;

__device__ __forceinline__ float bf2f(unsigned short u) {
    return __uint_as_float(((unsigned int)u) << 16);
}
__device__ __forceinline__ unsigned short f2bf(float f) {
    unsigned int x = __float_as_uint(f);
    unsigned int r = (x + 0x7FFFu + ((x >> 16) & 1u)) >> 16;
    return (unsigned short)r;
}
__device__ __forceinline__ float ldf(const void* p, long i, bool f32) {
    return f32 ? ((const float*)p)[i] : bf2f(((const unsigned short*)p)[i]);
}
__device__ __forceinline__ bool detect_f32(const unsigned short* Nv) {
    return Nv[0] == 0;   // N==1.0: bf16 halfword0=0x3F80, fp32 halfword0=0
}

// ---- DPP rotate-reduce helpers ----
template<int CTRL>
__device__ __forceinline__ float dppf(float x) {
    return __int_as_float(__builtin_amdgcn_update_dpp(
        0, __float_as_int(x), CTRL, 0xF, 0xF, true));
}
__device__ __forceinline__ float swz16(float x) {
    return __int_as_float(__builtin_amdgcn_ds_swizzle(__float_as_int(x), 0x401F));
}
__device__ __forceinline__ float red32max(float x) {
    x = fmaxf(x, dppf<0x128>(x));
    x = fmaxf(x, dppf<0x124>(x));
    x = fmaxf(x, dppf<0x122>(x));
    x = fmaxf(x, dppf<0x121>(x));
    return fmaxf(x, swz16(x));
}
__device__ __forceinline__ float red32sum(float x) {
    x += dppf<0x128>(x);
    x += dppf<0x124>(x);
    x += dppf<0x122>(x);
    x += dppf<0x121>(x);
    return x + swz16(x);
}
__device__ __forceinline__ float addx8_dpp(float x) {   // == x + shfl_xor(x,8)
    return x + dppf<0x128>(x);
}

// ---- packed bf16-pair MAC: 1 shl + 1 and + 1 v_pk_fma_f32 ----
// acc.{lo,hi} += {bf16lo(z), bf16hi(z)} * ap[SEL]
template<int SEL>
__device__ __forceinline__ void pkfma2(float2v& acc, unsigned int z, float2v ap) {
    float2v x;
    x[0] = __uint_as_float(z << 16);
    x[1] = __uint_as_float(z & 0xffff0000u);
    if (SEL == 0)
        asm("v_pk_fma_f32 %0, %1, %2, %0 op_sel:[0,0,0] op_sel_hi:[1,0,1]"
            : "+v"(acc) : "v"(x), "v"(ap));
    else
        asm("v_pk_fma_f32 %0, %1, %2, %0 op_sel:[0,1,0] op_sel_hi:[1,1,1]"
            : "+v"(acc) : "v"(x), "v"(ap));
}

// params block layout (floats)
#define P_WIH 0
#define P_WHH 3072
#define P_BIH 6144
#define P_BHH 6240
#define P_WR1 6336
#define P_BR1 6676
#define P_WR2 6686
#define P_BR2 6754
#define P_I   6756
#define P_R   6788
#define P_S   6820
#define P_IT  6852
#define P_RT  6884
#define P_N   6916
#define P_HX0 6917
#define P_TOT 6949

__global__ __launch_bounds__(256) void norm_params(
    const void* W1, const void* a1, const void* W2, const void* a2,
    const void* W_ih, const void* W_hh, const void* b_ih, const void* b_hh,
    const void* Wr1, const void* br1, const void* Wr2, const void* br2,
    const void* Iv, const void* Rv, const void* Sv, const void* Itv, const void* Rtv,
    const void* Nv, const void* hx0,
    float* __restrict__ P, unsigned short* __restrict__ WbT1,
    unsigned short* __restrict__ WbT2)
{
    bool f32 = detect_f32((const unsigned short*)Nv);
    int tid = threadIdx.x;
    struct Item { const void* p; int n; int off; };
    const Item items[15] = {
        {W_ih, 3072, P_WIH}, {W_hh, 3072, P_WHH}, {b_ih, 96, P_BIH}, {b_hh, 96, P_BHH},
        {Wr1, 340, P_WR1}, {br1, 10, P_BR1}, {Wr2, 68, P_WR2}, {br2, 2, P_BR2},
        {Iv, 32, P_I}, {Rv, 32, P_R}, {Sv, 32, P_S}, {Itv, 32, P_IT}, {Rtv, 32, P_RT},
        {Nv, 1, P_N}, {hx0, 32, P_HX0}
    };
    for (int it = 0; it < 15; it++)
        for (int i = tid; i < items[it].n; i += 256)
            P[items[it].off + i] = ldf(items[it].p, i, f32);

    for (int idx = tid; idx < 144 * 128; idx += 256) {
        int col = idx >> 7, k = idx & 127;
        float v = 0.f;
        if (col < 128) {
            int h = col >> 5, e = col & 31;
            v = ldf(W1, (h * 128 + k) * 32 + e, f32);
        } else if (col < 136) {
            int q = col - 128;
            int h = (q < 4) ? q : q - 4;
            int off = (q < 4) ? 0 : 32;
            float s = 0.f;
            for (int e = 0; e < 32; e++)
                s += ldf(W1, (h * 128 + k) * 32 + e, f32) * ldf(a1, h * 64 + off + e, f32);
            v = s;
        }
        WbT1[col * 128 + k] = f2bf(v);
    }
    for (int idx = tid; idx < 48 * 128; idx += 256) {
        int col = idx >> 7, k = idx & 127;
        float v = 0.f;
        if (col < 32) {
            v = ldf(W2, k * 32 + col, f32);
        } else if (col < 34) {
            int off = (col == 32) ? 0 : 32;
            float s = 0.f;
            for (int e = 0; e < 32; e++)
                s += ldf(W2, k * 32 + e, f32) * ldf(a2, off + e, f32);
            v = s;
        }
        WbT2[col * 128 + k] = f2bf(v);
    }
}

// ---------------------------------------------------------------------------
// K1/K3: C[M x NT*16] = X[M x 128] @ WbT^T via MFMA 16x16x32 bf16.
// ---------------------------------------------------------------------------
template<int NT, int HC, bool DYN>
__global__ __launch_bounds__(256) void gat_linear(
    const void* __restrict__ Xv, const unsigned short* __restrict__ WbT,
    unsigned short* __restrict__ Z, float* __restrict__ EL, float* __restrict__ ER,
    const unsigned short* __restrict__ Nv, long row0)
{
    constexpr int NCOL = NT * 16;
    constexpr int LDW  = 136;
    __shared__ unsigned short Ws[NCOL * LDW];
    int tid = threadIdx.x;
    for (int idx = tid; idx < NCOL * 16; idx += 256) {
        int col = idx >> 4, ch = idx & 15;
        *(uint4v*)(&Ws[col * LDW + ch * 8]) = *(const uint4v*)(&WbT[col * 128 + ch * 8]);
    }
    __syncthreads();

    bool f32 = DYN ? detect_f32(Nv) : false;
    int wave = tid >> 6, lane = tid & 63;
    int l15 = lane & 15, quad = lane >> 4;
    long lrow = (long)blockIdx.x * 64 + wave * 16;

    floatx4 acc[NT];
    floatx4 zz = {0.f, 0.f, 0.f, 0.f};
    #pragma unroll
    for (int i = 0; i < NT; i++) acc[i] = zz;

    long xoff = (row0 + lrow + l15) * 128 + quad * 8;
    #pragma unroll
    for (int kt = 0; kt < 4; kt++) {
        short8 afrag;
        if (DYN && f32) {
            const float* xr = (const float*)Xv + xoff + kt * 32;
            float4 u0 = ((const float4*)xr)[0];
            float4 u1 = ((const float4*)xr)[1];
            union { short8 v; unsigned short u[8]; } af;
            af.u[0] = f2bf(u0.x); af.u[1] = f2bf(u0.y);
            af.u[2] = f2bf(u0.z); af.u[3] = f2bf(u0.w);
            af.u[4] = f2bf(u1.x); af.u[5] = f2bf(u1.y);
            af.u[6] = f2bf(u1.z); af.u[7] = f2bf(u1.w);
            afrag = af.v;
        } else {
            afrag = *(const short8*)((const unsigned short*)Xv + xoff + kt * 32);
        }
        #pragma unroll
        for (int nt = 0; nt < NT; nt++) {
            short8 bfrag = *(const short8*)(&Ws[(nt * 16 + l15) * LDW + kt * 32 + quad * 8]);
            acc[nt] = __builtin_amdgcn_mfma_f32_16x16x32_bf16(afrag, bfrag, acc[nt], 0, 0, 0);
        }
    }

    #pragma unroll
    for (int nt = 0; nt < NT; nt++) {
        int col = nt * 16 + l15;
        #pragma unroll
        for (int r = 0; r < 4; r++) {
            long grow = lrow + quad * 4 + r;
            float v = acc[nt][r];
            if (col < HC * 32) {
                Z[grow * (HC * 32) + col] = f2bf(v);
            } else if (col < HC * 32 + HC) {
                EL[grow * HC + (col - HC * 32)] = v;
            } else if (col < HC * 32 + 2 * HC) {
                ER[grow * HC + (col - HC * 32 - HC)] = v;
            }
        }
    }
}

// ---------------------------------------------------------------------------
// K2: GAT1 aggregation, round-13: 4 nodes/wave (one phase-B pass) for TLP.
// 625 blocks/t x 16 nodes = 10000 exactly -> zero bounds checks.
// LDS 11.3 KB/block; VGPR ~48 -> up to 8 blocks/CU resident, hiding the
// L2 gather latency via waves instead of a register double-buffer the
// allocator kept collapsing.
// ---------------------------------------------------------------------------
__device__ __forceinline__ void iss8(uint4v* buf, const int4v sa, const int4v sb,
                                     const char* Zb, unsigned fb) {
    #pragma unroll
    for (int k = 0; k < 4; k++)
        buf[k] = *(const uint4v*)(Zb + (unsigned)(sa[k] * 256) + fb);
    #pragma unroll
    for (int k = 0; k < 4; k++)
        buf[4 + k] = *(const uint4v*)(Zb + (unsigned)(sb[k] * 256) + fb);
}
__device__ __forceinline__ void cons8(const uint4v* buf, const floatx4 ax, const floatx4 ay,
                                      float2v& c0, float2v& c1, float2v& c2, float2v& c3) {
    float2v a01 = {ax[0], ax[1]};
    float2v a23 = {ax[2], ax[3]};
    float2v a45 = {ay[0], ay[1]};
    float2v a67 = {ay[2], ay[3]};
    #define STEP(K, AP, SEL)              \
        pkfma2<SEL>(c0, buf[K].x, AP);    \
        pkfma2<SEL>(c1, buf[K].y, AP);    \
        pkfma2<SEL>(c2, buf[K].z, AP);    \
        pkfma2<SEL>(c3, buf[K].w, AP);
    STEP(0, a01, 0) STEP(1, a01, 1)
    STEP(2, a23, 0) STEP(3, a23, 1)
    STEP(4, a45, 0) STEP(5, a45, 1)
    STEP(6, a67, 0) STEP(7, a67, 1)
    #undef STEP
}

__global__ __launch_bounds__(256, 5) void gat1_aggr(
    const int* __restrict__ src,
    const unsigned short* __restrict__ Z,   // (TC*10000) x 128 bf16
    const float* __restrict__ EL,           // (TC*10000) x 4
    const float* __restrict__ ER,
    unsigned short* __restrict__ H1,        // (TC*10000) x 128 bf16
    int NX)
{
    __shared__ float als[4][4][4][36];      // [wave][node][head][d(+pad4)]
    __shared__ int   sid[4][4][32];         // [wave][node][d]
    int tid = threadIdx.x;
    int w = tid >> 6, lane = tid & 63;
    int d31 = lane & 31, g = lane >> 5;

    int bid = blockIdx.x;
    int xcd = bid % NX;
    int j   = bid / NX;
    int tq  = j / 625;
    int r   = j - tq * 625;
    int t   = tq * NX + xcd;
    int tb  = t * 10000;
    int n0  = r * 16 + w * 4;               // n0+3 <= 9999 always
    const char* Zb = (const char*)Z + (size_t)tb * 256;

    // ---- phase A: 4 batched softmaxes (DPP reductions) ----
    int sidx[4];
    float2v elv[4], erv[4];
    #pragma unroll
    for (int jj = 0; jj < 4; jj++)
        sidx[jj] = src[(n0 + jj) * 32 + d31];
    #pragma unroll
    for (int jj = 0; jj < 4; jj++)
        elv[jj] = *(const float2v*)(EL + (size_t)(tb + sidx[jj]) * 4 + g * 2);
    #pragma unroll
    for (int jj = 0; jj < 4; jj++)
        erv[jj] = *(const float2v*)(ER + (size_t)(tb + n0 + jj) * 4 + g * 2);
    float e0[4], e1[4];
    #pragma unroll
    for (int jj = 0; jj < 4; jj++) {
        float a = elv[jj][0] + erv[jj][0];
        float b = elv[jj][1] + erv[jj][1];
        e0[jj] = a >= 0.f ? a : 0.01f * a;
        e1[jj] = b >= 0.f ? b : 0.01f * b;
    }
    float x0[4], x1[4];
    #pragma unroll
    for (int jj = 0; jj < 4; jj++) {
        x0[jj] = __expf(e0[jj] - red32max(e0[jj]));
        x1[jj] = __expf(e1[jj] - red32max(e1[jj]));
    }
    #pragma unroll
    for (int jj = 0; jj < 4; jj++) {
        float r0 = __builtin_amdgcn_rcpf(red32sum(x0[jj]));
        float r1 = __builtin_amdgcn_rcpf(red32sum(x1[jj]));
        als[w][jj][2 * g + 0][d31] = x0[jj] * r0;
        als[w][jj][2 * g + 1][d31] = x1[jj] * r1;
        if (g == 0) sid[w][jj][d31] = sidx[jj];
    }
    __builtin_amdgcn_wave_barrier();

    // ---- phase B: per-lane full neighbor sum, all 4 nodes in one pass ----
    int u = lane >> 4;          // node within group of 4
    int f = lane & 15;          // dim chunk (8 dims)
    int h = f >> 2;             // head of this chunk
    unsigned fb = (unsigned)f * 16u;

    {
        int jj = u;
        const int* sp = &sid[w][jj][0];
        int4v sv0 = *(const int4v*)(sp + 0);
        int4v sv1 = *(const int4v*)(sp + 4);
        int4v sv2 = *(const int4v*)(sp + 8);
        int4v sv3 = *(const int4v*)(sp + 12);
        int4v sv4 = *(const int4v*)(sp + 16);
        int4v sv5 = *(const int4v*)(sp + 20);
        int4v sv6 = *(const int4v*)(sp + 24);
        int4v sv7 = *(const int4v*)(sp + 28);

        uint4v zA[8], zB[8];
        iss8(zA, sv0, sv1, Zb, fb);       // k 0..7 in flight
        iss8(zB, sv2, sv3, Zb, fb);       // k 8..15 in flight

        const float* ap_ = &als[w][jj][h][0];
        floatx4 av0 = *(const floatx4*)(ap_ + 0);
        floatx4 av1 = *(const floatx4*)(ap_ + 4);
        floatx4 av2 = *(const floatx4*)(ap_ + 8);
        floatx4 av3 = *(const floatx4*)(ap_ + 12);
        floatx4 av4 = *(const floatx4*)(ap_ + 16);
        floatx4 av5 = *(const floatx4*)(ap_ + 20);
        floatx4 av6 = *(const floatx4*)(ap_ + 24);
        floatx4 av7 = *(const floatx4*)(ap_ + 28);

        float2v c0 = {0.f, 0.f}, c1 = {0.f, 0.f}, c2 = {0.f, 0.f}, c3 = {0.f, 0.f};
        cons8(zA, av0, av1, c0, c1, c2, c3);
        iss8(zA, sv4, sv5, Zb, fb);       // k 16..23
        cons8(zB, av2, av3, c0, c1, c2, c3);
        iss8(zB, sv6, sv7, Zb, fb);       // k 24..31
        cons8(zA, av4, av5, c0, c1, c2, c3);
        cons8(zB, av6, av7, c0, c1, c2, c3);

        int n = n0 + jj;
        float p0 = fmaxf(c0[0], 0.f), p1 = fmaxf(c0[1], 0.f);
        float p2 = fmaxf(c1[0], 0.f), p3 = fmaxf(c1[1], 0.f);
        float p4 = fmaxf(c2[0], 0.f), p5 = fmaxf(c2[1], 0.f);
        float p6 = fmaxf(c3[0], 0.f), p7 = fmaxf(c3[1], 0.f);
        unsigned r0, r1, r2, r3;
        asm("v_cvt_pk_bf16_f32 %0, %1, %2" : "=v"(r0) : "v"(p0), "v"(p1));
        asm("v_cvt_pk_bf16_f32 %0, %1, %2" : "=v"(r1) : "v"(p2), "v"(p3));
        asm("v_cvt_pk_bf16_f32 %0, %1, %2" : "=v"(r2) : "v"(p4), "v"(p5));
        asm("v_cvt_pk_bf16_f32 %0, %1, %2" : "=v"(r3) : "v"(p6), "v"(p7));
        uint4v o = {r0, r1, r2, r3};
        __builtin_nontemporal_store(o,
            (uint4v*)((char*)H1 + (size_t)(tb + n) * 256 + fb));
    }
}

// ---------------------------------------------------------------------------
// K4: GAT2 aggregation + relu + max pool. (unchanged this round)
// ---------------------------------------------------------------------------
__global__ __launch_bounds__(256, 4) void gat2_aggr(
    const int* __restrict__ src,
    const unsigned short* __restrict__ Z2,  // (TC*10000) x 32 bf16
    const float* __restrict__ EL2,          // (TC*10000)
    const float* __restrict__ ER2,
    int* __restrict__ cur, int t0, int NX)
{
    __shared__ float als2[4][8][32];        // [wave][node-in-batch][d]
    __shared__ int bm[32];
    int tid = threadIdx.x, w = tid >> 6, lane = tid & 63;
    int d31 = lane & 31, g = lane >> 5;
    int g3 = lane >> 3, f7 = lane & 7;

    int bid = blockIdx.x;
    int xcd = bid % NX;
    int j   = bid / NX;
    int tq  = j / 157;
    int r   = j - tq * 157;
    int t   = tq * NX + xcd;
    int tb  = t * 10000;
    int n0  = r * 64 + w * 16;
    const char* Zb = (const char*)Z2 + (size_t)tb * 64;

    if (tid < 32) bm[tid] = 0;
    __syncthreads();

    float m4[4] = {0.f, 0.f, 0.f, 0.f};
    #pragma unroll
    for (int b = 0; b < 2; b++) {
        int nb = n0 + b * 8;
        float ev[8];
        #pragma unroll
        for (int jj = 0; jj < 8; jj++) {
            int n = nb + jj;
            bool ok = n < 10000;
            int sidx = ok ? src[n * 32 + d31] : 0;
            float e = ok ? (EL2[tb + sidx] + ER2[tb + n]) : 0.f;
            ev[jj] = e >= 0.f ? e : 0.01f * e;
        }
        float xv[8], sm[8];
        #pragma unroll
        for (int jj = 0; jj < 8; jj++)
            xv[jj] = __expf(ev[jj] - red32max(ev[jj]));
        #pragma unroll
        for (int jj = 0; jj < 8; jj++)
            sm[jj] = red32sum(xv[jj]);
        if (g == 0) {
            #pragma unroll
            for (int jj = 0; jj < 8; jj++)
                als2[w][jj][d31] = xv[jj] * __builtin_amdgcn_rcpf(sm[jj]);
        }
        __builtin_amdgcn_wave_barrier();

        #pragma unroll
        for (int jj = 0; jj < 8; jj++) {
            int n = nb + jj;
            if (n >= 10000) continue;
            floatx4 av4 = *(const floatx4*)&als2[w][jj][g3 * 4];   // broadcast b128
            int4v mv = *(const int4v*)(src + n * 32 + g3 * 4);     // group-uniform
            uint2v ldv[4];
            #pragma unroll
            for (int k = 0; k < 4; k++)
                ldv[k] = *(const uint2v*)(Zb + (unsigned int)(mv[k] * 64 + f7 * 8));
            float2v a01 = {av4[0], av4[1]};
            float2v a23 = {av4[2], av4[3]};
            float2v c01 = {0.f, 0.f}, c23 = {0.f, 0.f};
            pkfma2<0>(c01, ldv[0].x, a01); pkfma2<0>(c23, ldv[0].y, a01);
            pkfma2<1>(c01, ldv[1].x, a01); pkfma2<1>(c23, ldv[1].y, a01);
            pkfma2<0>(c01, ldv[2].x, a23); pkfma2<0>(c23, ldv[2].y, a23);
            pkfma2<1>(c01, ldv[3].x, a23); pkfma2<1>(c23, ldv[3].y, a23);
            float c0 = c01[0], c1 = c01[1], c2 = c23[0], c3 = c23[1];
            // reduce over lane-groups: xor8 (DPP), xor16 (swizzle), xor32 (shfl)
            c0 = addx8_dpp(c0); c1 = addx8_dpp(c1);
            c2 = addx8_dpp(c2); c3 = addx8_dpp(c3);
            c0 += swz16(c0); c1 += swz16(c1);
            c2 += swz16(c2); c3 += swz16(c3);
            c0 += __shfl_xor(c0, 32);
            c1 += __shfl_xor(c1, 32);
            c2 += __shfl_xor(c2, 32);
            c3 += __shfl_xor(c3, 32);
            m4[0] = fmaxf(m4[0], c0);
            m4[1] = fmaxf(m4[1], c1);
            m4[2] = fmaxf(m4[2], c2);
            m4[3] = fmaxf(m4[3], c3);
        }
        __builtin_amdgcn_wave_barrier();
    }
    if (lane < 8) {
        #pragma unroll
        for (int i = 0; i < 4; i++)
            atomicMax(&bm[f7 * 4 + i], __float_as_int(m4[i]));
    }
    __syncthreads();
    if (tid < 32) atomicMax(&cur[(t0 + t) * 32 + tid], bm[tid]);
}

// ---------------------------------------------------------------------------
// K5: GRU + readout + SIR physics. gi[t] precomputed (hx-independent).
// ---------------------------------------------------------------------------
__global__ __launch_bounds__(128) void gru_head(
    const float* __restrict__ P, const float* __restrict__ cur,
    void* __restrict__ outv, const unsigned short* __restrict__ Nv)
{
    bool f32 = detect_f32(Nv);
    __shared__ float Whh[96 * 32], giAll[32 * 96];
    __shared__ float hx[32], gh[96], nh[34];
    int tid = threadIdx.x;
    for (int i = tid; i < 96 * 32; i += 128)
        Whh[i] = P[P_WHH + i];
    for (int o = tid; o < 32 * 96; o += 128) {
        int t = o / 96, gg = o - t * 96;
        float s = P[P_BIH + gg];
        for (int k = 0; k < 32; k++)
            s += cur[t * 32 + k] * P[P_WIH + gg * 32 + k];
        giAll[o] = s;
    }
    if (tid < 32) hx[tid] = P[P_HX0 + tid];
    __syncthreads();

    for (int t = 0; t < 32; t++) {
        if (tid < 96) {
            float sh = 0.f;
            for (int k = 0; k < 32; k++)
                sh += hx[k] * Whh[tid * 32 + k];
            gh[tid] = sh + P[P_BHH + tid];
        }
        __syncthreads();
        if (tid < 32) {
            const float* gi = &giAll[t * 96];
            float r  = 1.f / (1.f + __expf(-(gi[tid] + gh[tid])));
            float zg = 1.f / (1.f + __expf(-(gi[32 + tid] + gh[32 + tid])));
            float ng = tanhf(gi[64 + tid] + r * gh[64 + tid]);
            float hv = (1.f - zg) * ng + zg * hx[tid];
            hx[tid] = hv;
            nh[tid] = hv;
            if (tid == 0) { nh[32] = P[P_IT + t]; nh[33] = P[P_RT + t]; }
        }
        __syncthreads();
        if (tid < 10) {
            float s = P[P_BR1 + tid];
            for (int k = 0; k < 34; k++) s += nh[k] * P[P_WR1 + tid * 34 + k];
            int i = tid >> 1;
            int oi = ((tid & 1) == 0) ? (t * 5 + i) : (160 + t * 5 + i);
            if (f32) ((float*)outv)[oi] = s;
            else     ((unsigned short*)outv)[oi] = f2bf(s);
        }
        if (tid == 64) {
            float ab0 = P[P_BR2 + 0], ab1 = P[P_BR2 + 1];
            for (int k = 0; k < 34; k++) {
                ab0 += nh[k] * P[P_WR2 + k];
                ab1 += nh[k] * P[P_WR2 + 34 + k];
            }
            float a_s = 1.f / (1.f + __expf(-ab0));
            float b_s = 1.f / (1.f + __expf(-ab1));
            float Ns = P[P_N];
            float lI = P[P_I + t], lR = P[P_R + t], lS = P[P_S + t];
            float dI = 0.f, dR = 0.f;
            for (int i = 0; i < 5; i++) {
                if (i > 0) { lI += dI; lR += dR; lS = Ns - lI - lR; }
                dI = a_s * lI * (lS / Ns) - b_s * lI;
                dR = b_s * lI;
                if (f32) {
                    ((float*)outv)[320 + t * 5 + i] = dI;
                    ((float*)outv)[480 + t * 5 + i] = dR;
                } else {
                    ((unsigned short*)outv)[320 + t * 5 + i] = f2bf(dI);
                    ((unsigned short*)outv)[480 + t * 5 + i] = f2bf(dR);
                }
            }
        }
        __syncthreads();
    }
}

extern "C" void kernel_launch(void* const* d_in, const int* in_sizes, int n_in,
                              void* d_out, int out_size, void* d_ws, size_t ws_size,
                              hipStream_t stream) {
    const void* h    = d_in[0];
    const int*  src  = (const int*)d_in[1];
    const void* Nv   = d_in[2];
    const void* Iv   = d_in[3];
    const void* Rv   = d_in[4];
    const void* Sv   = d_in[5];
    const void* Itv  = d_in[6];
    const void* Rtv  = d_in[7];
    const void* hx0  = d_in[8];
    const void* W1   = d_in[9];
    const void* a1   = d_in[10];
    const void* W2   = d_in[11];
    const void* a2   = d_in[12];
    const void* W_ih = d_in[13];
    const void* W_hh = d_in[14];
    const void* b_ih = d_in[15];
    const void* b_hh = d_in[16];
    const void* Wr1  = d_in[17];
    const void* br1  = d_in[18];
    const void* Wr2  = d_in[19];
    const void* br2  = d_in[20];
    const unsigned short* Nu = (const unsigned short*)Nv;

    int TC = 4;
    for (int c = 32; c >= 4; c >>= 1) {
        size_t need = (size_t)c * 10000 * (128 * 2 + 128 * 2 + 16 + 16) + (1 << 20);
        if (need <= ws_size) { TC = c; break; }
    }
    long CR = (long)TC * 10000;

    char* ws = (char*)d_ws;
    size_t off = 0;
    auto alloc = [&](size_t b) {
        void* p = ws + off;
        off += (b + 255) & ~(size_t)255;
        return p;
    };
    float*          Pb   = (float*)alloc(P_TOT * 4);
    unsigned short* WbT1 = (unsigned short*)alloc(144 * 128 * 2);
    unsigned short* WbT2 = (unsigned short*)alloc(48 * 128 * 2);
    float*          cur  = (float*)alloc(32 * 32 * 4);
    unsigned short* z1   = (unsigned short*)alloc((size_t)CR * 128 * 2);
    unsigned short* h1   = (unsigned short*)alloc((size_t)CR * 128 * 2);
    float*          el1  = (float*)alloc((size_t)CR * 4 * 4);
    float*          er1  = (float*)alloc((size_t)CR * 4 * 4);
    unsigned short* z2   = z1;
    float*          el2  = el1;
    float*          er2  = er1;

    (void)hipMemsetAsync(cur, 0, 32 * 32 * 4, stream);
    norm_params<<<1, 256, 0, stream>>>(W1, a1, W2, a2, W_ih, W_hh, b_ih, b_hh,
                                       Wr1, br1, Wr2, br2, Iv, Rv, Sv, Itv, Rtv,
                                       Nv, hx0, Pb, WbT1, WbT2);
    int nchunks = 32 / TC;
    int g1 = (int)(CR / 64);
    int NX = TC < 8 ? TC : 8;     // t-slice -> XCD interleave factor
    int TQ = TC / NX;
    for (int c = 0; c < nchunks; c++) {
        long row0 = (long)c * CR;
        gat_linear<9, 4, true><<<g1, 256, 0, stream>>>(h, WbT1, z1, el1, er1, Nu, row0);
        gat1_aggr<<<NX * 625 * TQ, 256, 0, stream>>>(src, z1, el1, er1, h1, NX);
        gat_linear<3, 1, false><<<g1, 256, 0, stream>>>(h1, WbT2, z2, el2, er2, Nu, 0);
        gat2_aggr<<<NX * 157 * TQ, 256, 0, stream>>>(src, z2, el2, er2, (int*)cur, c * TC, NX);
    }
    gru_head<<<1, 128, 0, stream>>>(Pb, cur, d_out, Nu);
}

// Round 5
// 632.774 us; speedup vs baseline: 1.0307x; 1.0307x over previous
//
#include <hip/hip_runtime.h>

typedef __attribute__((ext_vector_type(8))) short short8;
typedef __attribute__((ext_vector_type(4))) float floatx4;
typedef __attribute__((ext_vector_type(2))) float float2v;
typedef __attribute__((ext_vector_type(4))) unsigned int uint4v;
typedef __attribute__((ext_vector_type(4))) int int4v;
typedef __attribute__((ext_vector_type(2))) unsigned int uint2v;

__device__ __forceinline__ float bf2f(unsigned short u) {
    return __uint_as_float(((unsigned int)u) << 16);
}
__device__ __forceinline__ unsigned short f2bf(float f) {
    unsigned int x = __float_as_uint(f);
    unsigned int r = (x + 0x7FFFu + ((x >> 16) & 1u)) >> 16;
    return (unsigned short)r;
}
__device__ __forceinline__ float ldf(const void* p, long i, bool f32) {
    return f32 ? ((const float*)p)[i] : bf2f(((const unsigned short*)p)[i]);
}
__device__ __forceinline__ bool detect_f32(const unsigned short* Nv) {
    return Nv[0] == 0;   // N==1.0: bf16 halfword0=0x3F80, fp32 halfword0=0
}

// ---- DPP rotate-reduce helpers ----
template<int CTRL>
__device__ __forceinline__ float dppf(float x) {
    return __int_as_float(__builtin_amdgcn_update_dpp(
        0, __float_as_int(x), CTRL, 0xF, 0xF, true));
}
__device__ __forceinline__ float swz16(float x) {
    return __int_as_float(__builtin_amdgcn_ds_swizzle(__float_as_int(x), 0x401F));
}
__device__ __forceinline__ float red32max(float x) {
    x = fmaxf(x, dppf<0x128>(x));
    x = fmaxf(x, dppf<0x124>(x));
    x = fmaxf(x, dppf<0x122>(x));
    x = fmaxf(x, dppf<0x121>(x));
    return fmaxf(x, swz16(x));
}
__device__ __forceinline__ float red32sum(float x) {
    x += dppf<0x128>(x);
    x += dppf<0x124>(x);
    x += dppf<0x122>(x);
    x += dppf<0x121>(x);
    return x + swz16(x);
}
__device__ __forceinline__ float addx8_dpp(float x) {   // == x + shfl_xor(x,8)
    return x + dppf<0x128>(x);
}

// ---- packed bf16-pair MAC: 1 shl + 1 and + 1 v_pk_fma_f32 ----
// acc.{lo,hi} += {bf16lo(z), bf16hi(z)} * ap[SEL]
template<int SEL>
__device__ __forceinline__ void pkfma2(float2v& acc, unsigned int z, float2v ap) {
    float2v x;
    x[0] = __uint_as_float(z << 16);
    x[1] = __uint_as_float(z & 0xffff0000u);
    if (SEL == 0)
        asm("v_pk_fma_f32 %0, %1, %2, %0 op_sel:[0,0,0] op_sel_hi:[1,0,1]"
            : "+v"(acc) : "v"(x), "v"(ap));
    else
        asm("v_pk_fma_f32 %0, %1, %2, %0 op_sel:[0,1,0] op_sel_hi:[1,1,1]"
            : "+v"(acc) : "v"(x), "v"(ap));
}

// params block layout (floats)
#define P_WIH 0
#define P_WHH 3072
#define P_BIH 6144
#define P_BHH 6240
#define P_WR1 6336
#define P_BR1 6676
#define P_WR2 6686
#define P_BR2 6754
#define P_I   6756
#define P_R   6788
#define P_S   6820
#define P_IT  6852
#define P_RT  6884
#define P_N   6916
#define P_HX0 6917
#define P_TOT 6949

__global__ __launch_bounds__(256) void norm_params(
    const void* W1, const void* a1, const void* W2, const void* a2,
    const void* W_ih, const void* W_hh, const void* b_ih, const void* b_hh,
    const void* Wr1, const void* br1, const void* Wr2, const void* br2,
    const void* Iv, const void* Rv, const void* Sv, const void* Itv, const void* Rtv,
    const void* Nv, const void* hx0,
    float* __restrict__ P, unsigned short* __restrict__ WbT1,
    unsigned short* __restrict__ WbT2)
{
    bool f32 = detect_f32((const unsigned short*)Nv);
    int tid = threadIdx.x;
    struct Item { const void* p; int n; int off; };
    const Item items[15] = {
        {W_ih, 3072, P_WIH}, {W_hh, 3072, P_WHH}, {b_ih, 96, P_BIH}, {b_hh, 96, P_BHH},
        {Wr1, 340, P_WR1}, {br1, 10, P_BR1}, {Wr2, 68, P_WR2}, {br2, 2, P_BR2},
        {Iv, 32, P_I}, {Rv, 32, P_R}, {Sv, 32, P_S}, {Itv, 32, P_IT}, {Rtv, 32, P_RT},
        {Nv, 1, P_N}, {hx0, 32, P_HX0}
    };
    for (int it = 0; it < 15; it++)
        for (int i = tid; i < items[it].n; i += 256)
            P[items[it].off + i] = ldf(items[it].p, i, f32);

    for (int idx = tid; idx < 144 * 128; idx += 256) {
        int col = idx >> 7, k = idx & 127;
        float v = 0.f;
        if (col < 128) {
            int h = col >> 5, e = col & 31;
            v = ldf(W1, (h * 128 + k) * 32 + e, f32);
        } else if (col < 136) {
            int q = col - 128;
            int h = (q < 4) ? q : q - 4;
            int off = (q < 4) ? 0 : 32;
            float s = 0.f;
            for (int e = 0; e < 32; e++)
                s += ldf(W1, (h * 128 + k) * 32 + e, f32) * ldf(a1, h * 64 + off + e, f32);
            v = s;
        }
        WbT1[col * 128 + k] = f2bf(v);
    }
    for (int idx = tid; idx < 48 * 128; idx += 256) {
        int col = idx >> 7, k = idx & 127;
        float v = 0.f;
        if (col < 32) {
            v = ldf(W2, k * 32 + col, f32);
        } else if (col < 34) {
            int off = (col == 32) ? 0 : 32;
            float s = 0.f;
            for (int e = 0; e < 32; e++)
                s += ldf(W2, k * 32 + e, f32) * ldf(a2, off + e, f32);
            v = s;
        }
        WbT2[col * 128 + k] = f2bf(v);
    }
}

// ---------------------------------------------------------------------------
// K1/K3: C[M x NT*16] = X[M x 128] @ WbT^T via MFMA 16x16x32 bf16.
// ---------------------------------------------------------------------------
template<int NT, int HC, bool DYN>
__global__ __launch_bounds__(256) void gat_linear(
    const void* __restrict__ Xv, const unsigned short* __restrict__ WbT,
    unsigned short* __restrict__ Z, float* __restrict__ EL, float* __restrict__ ER,
    const unsigned short* __restrict__ Nv, long row0)
{
    constexpr int NCOL = NT * 16;
    constexpr int LDW  = 136;
    __shared__ unsigned short Ws[NCOL * LDW];
    int tid = threadIdx.x;
    for (int idx = tid; idx < NCOL * 16; idx += 256) {
        int col = idx >> 4, ch = idx & 15;
        *(uint4v*)(&Ws[col * LDW + ch * 8]) = *(const uint4v*)(&WbT[col * 128 + ch * 8]);
    }
    __syncthreads();

    bool f32 = DYN ? detect_f32(Nv) : false;
    int wave = tid >> 6, lane = tid & 63;
    int l15 = lane & 15, quad = lane >> 4;
    long lrow = (long)blockIdx.x * 64 + wave * 16;

    floatx4 acc[NT];
    floatx4 zz = {0.f, 0.f, 0.f, 0.f};
    #pragma unroll
    for (int i = 0; i < NT; i++) acc[i] = zz;

    long xoff = (row0 + lrow + l15) * 128 + quad * 8;
    #pragma unroll
    for (int kt = 0; kt < 4; kt++) {
        short8 afrag;
        if (DYN && f32) {
            const float* xr = (const float*)Xv + xoff + kt * 32;
            float4 u0 = ((const float4*)xr)[0];
            float4 u1 = ((const float4*)xr)[1];
            union { short8 v; unsigned short u[8]; } af;
            af.u[0] = f2bf(u0.x); af.u[1] = f2bf(u0.y);
            af.u[2] = f2bf(u0.z); af.u[3] = f2bf(u0.w);
            af.u[4] = f2bf(u1.x); af.u[5] = f2bf(u1.y);
            af.u[6] = f2bf(u1.z); af.u[7] = f2bf(u1.w);
            afrag = af.v;
        } else {
            afrag = *(const short8*)((const unsigned short*)Xv + xoff + kt * 32);
        }
        #pragma unroll
        for (int nt = 0; nt < NT; nt++) {
            short8 bfrag = *(const short8*)(&Ws[(nt * 16 + l15) * LDW + kt * 32 + quad * 8]);
            acc[nt] = __builtin_amdgcn_mfma_f32_16x16x32_bf16(afrag, bfrag, acc[nt], 0, 0, 0);
        }
    }

    #pragma unroll
    for (int nt = 0; nt < NT; nt++) {
        int col = nt * 16 + l15;
        #pragma unroll
        for (int r = 0; r < 4; r++) {
            long grow = lrow + quad * 4 + r;
            float v = acc[nt][r];
            if (col < HC * 32) {
                Z[grow * (HC * 32) + col] = f2bf(v);
            } else if (col < HC * 32 + HC) {
                EL[grow * HC + (col - HC * 32)] = v;
            } else if (col < HC * 32 + 2 * HC) {
                ER[grow * HC + (col - HC * 32 - HC)] = v;
            }
        }
    }
}

// ---------------------------------------------------------------------------
// K2: GAT1 aggregation, round-14.
// Phase A de-dup: one float4 EL load per lane (half hf owns a node) ->
// 128 TA lookups instead of 256; ER as float4 (2 instrs). Each 32-lane
// half computes softmax for its own nodes (hf, 2+hf); DPP reductions are
// per-half so chain count is unchanged. als contents identical to before.
// Phase B unchanged (per-lane full neighbor sum, 4 nodes, pk_fma MACs).
// ---------------------------------------------------------------------------
__device__ __forceinline__ void iss8(uint4v* buf, const int4v sa, const int4v sb,
                                     const char* Zb, unsigned fb) {
    #pragma unroll
    for (int k = 0; k < 4; k++)
        buf[k] = *(const uint4v*)(Zb + (unsigned)(sa[k] * 256) + fb);
    #pragma unroll
    for (int k = 0; k < 4; k++)
        buf[4 + k] = *(const uint4v*)(Zb + (unsigned)(sb[k] * 256) + fb);
}
__device__ __forceinline__ void cons8(const uint4v* buf, const floatx4 ax, const floatx4 ay,
                                      float2v& c0, float2v& c1, float2v& c2, float2v& c3) {
    float2v a01 = {ax[0], ax[1]};
    float2v a23 = {ax[2], ax[3]};
    float2v a45 = {ay[0], ay[1]};
    float2v a67 = {ay[2], ay[3]};
    #define STEP(K, AP, SEL)              \
        pkfma2<SEL>(c0, buf[K].x, AP);    \
        pkfma2<SEL>(c1, buf[K].y, AP);    \
        pkfma2<SEL>(c2, buf[K].z, AP);    \
        pkfma2<SEL>(c3, buf[K].w, AP);
    STEP(0, a01, 0) STEP(1, a01, 1)
    STEP(2, a23, 0) STEP(3, a23, 1)
    STEP(4, a45, 0) STEP(5, a45, 1)
    STEP(6, a67, 0) STEP(7, a67, 1)
    #undef STEP
}

__global__ __launch_bounds__(256, 5) void gat1_aggr(
    const int* __restrict__ src,
    const unsigned short* __restrict__ Z,   // (TC*10000) x 128 bf16
    const float* __restrict__ EL,           // (TC*10000) x 4
    const float* __restrict__ ER,
    unsigned short* __restrict__ H1,        // (TC*10000) x 128 bf16
    int NX)
{
    __shared__ float als[4][4][4][36];      // [wave][node][head][d(+pad4)]
    __shared__ int   sid[4][4][32];         // [wave][node][d]
    int tid = threadIdx.x;
    int w = tid >> 6, lane = tid & 63;
    int d31 = lane & 31, hf = lane >> 5;

    int bid = blockIdx.x;
    int xcd = bid % NX;
    int j   = bid / NX;
    int tq  = j / 625;
    int r   = j - tq * 625;
    int t   = tq * NX + xcd;
    int tb  = t * 10000;
    int n0  = r * 16 + w * 4;               // n0+3 <= 9999 always
    const char* Zb = (const char*)Z + (size_t)tb * 256;

    // ---- phase A: 4 softmaxes, de-duplicated gathers ----
    int sidx[4];
    #pragma unroll
    for (int jj = 0; jj < 4; jj++)
        sidx[jj] = src[(n0 + jj) * 32 + d31];

    int mA = hf ? sidx[1] : sidx[0];
    int mB = hf ? sidx[3] : sidx[2];
    floatx4 elA = *(const floatx4*)(EL + (size_t)(tb + mA) * 4);
    floatx4 elB = *(const floatx4*)(EL + (size_t)(tb + mB) * 4);
    floatx4 erA = *(const floatx4*)(ER + (size_t)(tb + n0 + hf) * 4);
    floatx4 erB = *(const floatx4*)(ER + (size_t)(tb + n0 + 2 + hf) * 4);

    float xA[4], xB[4];
    #pragma unroll
    for (int h = 0; h < 4; h++) {
        float a = elA[h] + erA[h];
        float b = elB[h] + erB[h];
        a = a >= 0.f ? a : 0.01f * a;
        b = b >= 0.f ? b : 0.01f * b;
        xA[h] = __expf(a - red32max(a));
        xB[h] = __expf(b - red32max(b));
    }
    #pragma unroll
    for (int h = 0; h < 4; h++) {
        als[w][hf][h][d31]     = xA[h] * __builtin_amdgcn_rcpf(red32sum(xA[h]));
        als[w][2 + hf][h][d31] = xB[h] * __builtin_amdgcn_rcpf(red32sum(xB[h]));
    }
    if (hf == 0) {
        #pragma unroll
        for (int jj = 0; jj < 4; jj++)
            sid[w][jj][d31] = sidx[jj];
    }
    __builtin_amdgcn_wave_barrier();

    // ---- phase B: per-lane full neighbor sum, all 4 nodes in one pass ----
    int u = lane >> 4;          // node within group of 4
    int f = lane & 15;          // dim chunk (8 dims)
    int h = f >> 2;             // head of this chunk
    unsigned fb = (unsigned)f * 16u;

    {
        int jj = u;
        const int* sp = &sid[w][jj][0];
        int4v sv0 = *(const int4v*)(sp + 0);
        int4v sv1 = *(const int4v*)(sp + 4);
        int4v sv2 = *(const int4v*)(sp + 8);
        int4v sv3 = *(const int4v*)(sp + 12);
        int4v sv4 = *(const int4v*)(sp + 16);
        int4v sv5 = *(const int4v*)(sp + 20);
        int4v sv6 = *(const int4v*)(sp + 24);
        int4v sv7 = *(const int4v*)(sp + 28);

        uint4v zA[8], zB[8];
        iss8(zA, sv0, sv1, Zb, fb);       // k 0..7 in flight
        iss8(zB, sv2, sv3, Zb, fb);       // k 8..15 in flight

        const float* ap_ = &als[w][jj][h][0];
        floatx4 av0 = *(const floatx4*)(ap_ + 0);
        floatx4 av1 = *(const floatx4*)(ap_ + 4);
        floatx4 av2 = *(const floatx4*)(ap_ + 8);
        floatx4 av3 = *(const floatx4*)(ap_ + 12);
        floatx4 av4 = *(const floatx4*)(ap_ + 16);
        floatx4 av5 = *(const floatx4*)(ap_ + 20);
        floatx4 av6 = *(const floatx4*)(ap_ + 24);
        floatx4 av7 = *(const floatx4*)(ap_ + 28);

        float2v c0 = {0.f, 0.f}, c1 = {0.f, 0.f}, c2 = {0.f, 0.f}, c3 = {0.f, 0.f};
        cons8(zA, av0, av1, c0, c1, c2, c3);
        iss8(zA, sv4, sv5, Zb, fb);       // k 16..23
        cons8(zB, av2, av3, c0, c1, c2, c3);
        iss8(zB, sv6, sv7, Zb, fb);       // k 24..31
        cons8(zA, av4, av5, c0, c1, c2, c3);
        cons8(zB, av6, av7, c0, c1, c2, c3);

        int n = n0 + jj;
        float p0 = fmaxf(c0[0], 0.f), p1 = fmaxf(c0[1], 0.f);
        float p2 = fmaxf(c1[0], 0.f), p3 = fmaxf(c1[1], 0.f);
        float p4 = fmaxf(c2[0], 0.f), p5 = fmaxf(c2[1], 0.f);
        float p6 = fmaxf(c3[0], 0.f), p7 = fmaxf(c3[1], 0.f);
        unsigned r0, r1, r2, r3;
        asm("v_cvt_pk_bf16_f32 %0, %1, %2" : "=v"(r0) : "v"(p0), "v"(p1));
        asm("v_cvt_pk_bf16_f32 %0, %1, %2" : "=v"(r1) : "v"(p2), "v"(p3));
        asm("v_cvt_pk_bf16_f32 %0, %1, %2" : "=v"(r2) : "v"(p4), "v"(p5));
        asm("v_cvt_pk_bf16_f32 %0, %1, %2" : "=v"(r3) : "v"(p6), "v"(p7));
        uint4v o = {r0, r1, r2, r3};
        __builtin_nontemporal_store(o,
            (uint4v*)((char*)H1 + (size_t)(tb + n) * 256 + fb));
    }
}

// ---------------------------------------------------------------------------
// K4: GAT2 aggregation + relu + max pool. Round-14: softmax de-dup — each
// 32-lane half owns node jj = 2k+g, halving src/EL2/ER2 gathers, exps and
// reduction chains. als2 written unconditionally (64 distinct slots).
// Aggregation loop unchanged.
// ---------------------------------------------------------------------------
__global__ __launch_bounds__(256, 4) void gat2_aggr(
    const int* __restrict__ src,
    const unsigned short* __restrict__ Z2,  // (TC*10000) x 32 bf16
    const float* __restrict__ EL2,          // (TC*10000)
    const float* __restrict__ ER2,
    int* __restrict__ cur, int t0, int NX)
{
    __shared__ float als2[4][8][32];        // [wave][node-in-batch][d]
    __shared__ int bm[32];
    int tid = threadIdx.x, w = tid >> 6, lane = tid & 63;
    int d31 = lane & 31, g = lane >> 5;
    int g3 = lane >> 3, f7 = lane & 7;

    int bid = blockIdx.x;
    int xcd = bid % NX;
    int j   = bid / NX;
    int tq  = j / 157;
    int r   = j - tq * 157;
    int t   = tq * NX + xcd;
    int tb  = t * 10000;
    int n0  = r * 64 + w * 16;
    const char* Zb = (const char*)Z2 + (size_t)tb * 64;

    if (tid < 32) bm[tid] = 0;
    __syncthreads();

    float m4[4] = {0.f, 0.f, 0.f, 0.f};
    #pragma unroll
    for (int b = 0; b < 2; b++) {
        int nb = n0 + b * 8;
        float xv[4];
        #pragma unroll
        for (int k = 0; k < 4; k++) {
            int n = nb + 2 * k + g;
            n = n > 9999 ? 9999 : n;          // clamp (phase B guards real bound)
            int m = src[n * 32 + d31];
            float e = EL2[tb + m] + ER2[tb + n];
            e = e >= 0.f ? e : 0.01f * e;
            xv[k] = __expf(e - red32max(e));
        }
        #pragma unroll
        for (int k = 0; k < 4; k++)
            als2[w][2 * k + g][d31] = xv[k] * __builtin_amdgcn_rcpf(red32sum(xv[k]));
        __builtin_amdgcn_wave_barrier();

        #pragma unroll
        for (int jj = 0; jj < 8; jj++) {
            int n = nb + jj;
            if (n >= 10000) continue;
            floatx4 av4 = *(const floatx4*)&als2[w][jj][g3 * 4];   // broadcast b128
            int4v mv = *(const int4v*)(src + n * 32 + g3 * 4);     // group-uniform
            uint2v ldv[4];
            #pragma unroll
            for (int k = 0; k < 4; k++)
                ldv[k] = *(const uint2v*)(Zb + (unsigned int)(mv[k] * 64 + f7 * 8));
            float2v a01 = {av4[0], av4[1]};
            float2v a23 = {av4[2], av4[3]};
            float2v c01 = {0.f, 0.f}, c23 = {0.f, 0.f};
            pkfma2<0>(c01, ldv[0].x, a01); pkfma2<0>(c23, ldv[0].y, a01);
            pkfma2<1>(c01, ldv[1].x, a01); pkfma2<1>(c23, ldv[1].y, a01);
            pkfma2<0>(c01, ldv[2].x, a23); pkfma2<0>(c23, ldv[2].y, a23);
            pkfma2<1>(c01, ldv[3].x, a23); pkfma2<1>(c23, ldv[3].y, a23);
            float c0 = c01[0], c1 = c01[1], c2 = c23[0], c3 = c23[1];
            // reduce over lane-groups: xor8 (DPP), xor16 (swizzle), xor32 (shfl)
            c0 = addx8_dpp(c0); c1 = addx8_dpp(c1);
            c2 = addx8_dpp(c2); c3 = addx8_dpp(c3);
            c0 += swz16(c0); c1 += swz16(c1);
            c2 += swz16(c2); c3 += swz16(c3);
            c0 += __shfl_xor(c0, 32);
            c1 += __shfl_xor(c1, 32);
            c2 += __shfl_xor(c2, 32);
            c3 += __shfl_xor(c3, 32);
            m4[0] = fmaxf(m4[0], c0);
            m4[1] = fmaxf(m4[1], c1);
            m4[2] = fmaxf(m4[2], c2);
            m4[3] = fmaxf(m4[3], c3);
        }
        __builtin_amdgcn_wave_barrier();
    }
    if (lane < 8) {
        #pragma unroll
        for (int i = 0; i < 4; i++)
            atomicMax(&bm[f7 * 4 + i], __float_as_int(m4[i]));
    }
    __syncthreads();
    if (tid < 32) atomicMax(&cur[(t0 + t) * 32 + tid], bm[tid]);
}

// ---------------------------------------------------------------------------
// K5: GRU + readout + SIR physics. gi[t] precomputed (hx-independent).
// ---------------------------------------------------------------------------
__global__ __launch_bounds__(128) void gru_head(
    const float* __restrict__ P, const float* __restrict__ cur,
    void* __restrict__ outv, const unsigned short* __restrict__ Nv)
{
    bool f32 = detect_f32(Nv);
    __shared__ float Whh[96 * 32], giAll[32 * 96];
    __shared__ float hx[32], gh[96], nh[34];
    int tid = threadIdx.x;
    for (int i = tid; i < 96 * 32; i += 128)
        Whh[i] = P[P_WHH + i];
    for (int o = tid; o < 32 * 96; o += 128) {
        int t = o / 96, gg = o - t * 96;
        float s = P[P_BIH + gg];
        for (int k = 0; k < 32; k++)
            s += cur[t * 32 + k] * P[P_WIH + gg * 32 + k];
        giAll[o] = s;
    }
    if (tid < 32) hx[tid] = P[P_HX0 + tid];
    __syncthreads();

    for (int t = 0; t < 32; t++) {
        if (tid < 96) {
            float sh = 0.f;
            for (int k = 0; k < 32; k++)
                sh += hx[k] * Whh[tid * 32 + k];
            gh[tid] = sh + P[P_BHH + tid];
        }
        __syncthreads();
        if (tid < 32) {
            const float* gi = &giAll[t * 96];
            float r  = 1.f / (1.f + __expf(-(gi[tid] + gh[tid])));
            float zg = 1.f / (1.f + __expf(-(gi[32 + tid] + gh[32 + tid])));
            float ng = tanhf(gi[64 + tid] + r * gh[64 + tid]);
            float hv = (1.f - zg) * ng + zg * hx[tid];
            hx[tid] = hv;
            nh[tid] = hv;
            if (tid == 0) { nh[32] = P[P_IT + t]; nh[33] = P[P_RT + t]; }
        }
        __syncthreads();
        if (tid < 10) {
            float s = P[P_BR1 + tid];
            for (int k = 0; k < 34; k++) s += nh[k] * P[P_WR1 + tid * 34 + k];
            int i = tid >> 1;
            int oi = ((tid & 1) == 0) ? (t * 5 + i) : (160 + t * 5 + i);
            if (f32) ((float*)outv)[oi] = s;
            else     ((unsigned short*)outv)[oi] = f2bf(s);
        }
        if (tid == 64) {
            float ab0 = P[P_BR2 + 0], ab1 = P[P_BR2 + 1];
            for (int k = 0; k < 34; k++) {
                ab0 += nh[k] * P[P_WR2 + k];
                ab1 += nh[k] * P[P_WR2 + 34 + k];
            }
            float a_s = 1.f / (1.f + __expf(-ab0));
            float b_s = 1.f / (1.f + __expf(-ab1));
            float Ns = P[P_N];
            float lI = P[P_I + t], lR = P[P_R + t], lS = P[P_S + t];
            float dI = 0.f, dR = 0.f;
            for (int i = 0; i < 5; i++) {
                if (i > 0) { lI += dI; lR += dR; lS = Ns - lI - lR; }
                dI = a_s * lI * (lS / Ns) - b_s * lI;
                dR = b_s * lI;
                if (f32) {
                    ((float*)outv)[320 + t * 5 + i] = dI;
                    ((float*)outv)[480 + t * 5 + i] = dR;
                } else {
                    ((unsigned short*)outv)[320 + t * 5 + i] = f2bf(dI);
                    ((unsigned short*)outv)[480 + t * 5 + i] = f2bf(dR);
                }
            }
        }
        __syncthreads();
    }
}

extern "C" void kernel_launch(void* const* d_in, const int* in_sizes, int n_in,
                              void* d_out, int out_size, void* d_ws, size_t ws_size,
                              hipStream_t stream) {
    const void* h    = d_in[0];
    const int*  src  = (const int*)d_in[1];
    const void* Nv   = d_in[2];
    const void* Iv   = d_in[3];
    const void* Rv   = d_in[4];
    const void* Sv   = d_in[5];
    const void* Itv  = d_in[6];
    const void* Rtv  = d_in[7];
    const void* hx0  = d_in[8];
    const void* W1   = d_in[9];
    const void* a1   = d_in[10];
    const void* W2   = d_in[11];
    const void* a2   = d_in[12];
    const void* W_ih = d_in[13];
    const void* W_hh = d_in[14];
    const void* b_ih = d_in[15];
    const void* b_hh = d_in[16];
    const void* Wr1  = d_in[17];
    const void* br1  = d_in[18];
    const void* Wr2  = d_in[19];
    const void* br2  = d_in[20];
    const unsigned short* Nu = (const unsigned short*)Nv;

    int TC = 4;
    for (int c = 32; c >= 4; c >>= 1) {
        size_t need = (size_t)c * 10000 * (128 * 2 + 128 * 2 + 16 + 16) + (1 << 20);
        if (need <= ws_size) { TC = c; break; }
    }
    long CR = (long)TC * 10000;

    char* ws = (char*)d_ws;
    size_t off = 0;
    auto alloc = [&](size_t b) {
        void* p = ws + off;
        off += (b + 255) & ~(size_t)255;
        return p;
    };
    float*          Pb   = (float*)alloc(P_TOT * 4);
    unsigned short* WbT1 = (unsigned short*)alloc(144 * 128 * 2);
    unsigned short* WbT2 = (unsigned short*)alloc(48 * 128 * 2);
    float*          cur  = (float*)alloc(32 * 32 * 4);
    unsigned short* z1   = (unsigned short*)alloc((size_t)CR * 128 * 2);
    unsigned short* h1   = (unsigned short*)alloc((size_t)CR * 128 * 2);
    float*          el1  = (float*)alloc((size_t)CR * 4 * 4);
    float*          er1  = (float*)alloc((size_t)CR * 4 * 4);
    unsigned short* z2   = z1;
    float*          el2  = el1;
    float*          er2  = er1;

    (void)hipMemsetAsync(cur, 0, 32 * 32 * 4, stream);
    norm_params<<<1, 256, 0, stream>>>(W1, a1, W2, a2, W_ih, W_hh, b_ih, b_hh,
                                       Wr1, br1, Wr2, br2, Iv, Rv, Sv, Itv, Rtv,
                                       Nv, hx0, Pb, WbT1, WbT2);
    int nchunks = 32 / TC;
    int g1 = (int)(CR / 64);
    int NX = TC < 8 ? TC : 8;     // t-slice -> XCD interleave factor
    int TQ = TC / NX;
    for (int c = 0; c < nchunks; c++) {
        long row0 = (long)c * CR;
        gat_linear<9, 4, true><<<g1, 256, 0, stream>>>(h, WbT1, z1, el1, er1, Nu, row0);
        gat1_aggr<<<NX * 625 * TQ, 256, 0, stream>>>(src, z1, el1, er1, h1, NX);
        gat_linear<3, 1, false><<<g1, 256, 0, stream>>>(h1, WbT2, z2, el2, er2, Nu, 0);
        gat2_aggr<<<NX * 157 * TQ, 256, 0, stream>>>(src, z2, el2, er2, (int*)cur, c * TC, NX);
    }
    gru_head<<<1, 128, 0, stream>>>(Pb, cur, d_out, Nu);
}

// Round 6
// 587.724 us; speedup vs baseline: 1.1097x; 1.0767x over previous
//
#include <hip/hip_runtime.h>

typedef __attribute__((ext_vector_type(8))) short short8;
typedef __attribute__((ext_vector_type(4))) float floatx4;
typedef __attribute__((ext_vector_type(2))) float float2v;
typedef __attribute__((ext_vector_type(4))) unsigned int uint4v;
typedef __attribute__((ext_vector_type(4))) int int4v;
typedef __attribute__((ext_vector_type(2))) unsigned int uint2v;

__device__ __forceinline__ float bf2f(unsigned short u) {
    return __uint_as_float(((unsigned int)u) << 16);
}
__device__ __forceinline__ unsigned short f2bf(float f) {
    unsigned int x = __float_as_uint(f);
    unsigned int r = (x + 0x7FFFu + ((x >> 16) & 1u)) >> 16;
    return (unsigned short)r;
}
__device__ __forceinline__ float ldf(const void* p, long i, bool f32) {
    return f32 ? ((const float*)p)[i] : bf2f(((const unsigned short*)p)[i]);
}
__device__ __forceinline__ bool detect_f32(const unsigned short* Nv) {
    return Nv[0] == 0;   // N==1.0: bf16 halfword0=0x3F80, fp32 halfword0=0
}

// ---- DPP rotate-reduce helpers ----
template<int CTRL>
__device__ __forceinline__ float dppf(float x) {
    return __int_as_float(__builtin_amdgcn_update_dpp(
        0, __float_as_int(x), CTRL, 0xF, 0xF, true));
}
__device__ __forceinline__ float swz16(float x) {
    return __int_as_float(__builtin_amdgcn_ds_swizzle(__float_as_int(x), 0x401F));
}
__device__ __forceinline__ float red32max(float x) {
    x = fmaxf(x, dppf<0x128>(x));
    x = fmaxf(x, dppf<0x124>(x));
    x = fmaxf(x, dppf<0x122>(x));
    x = fmaxf(x, dppf<0x121>(x));
    return fmaxf(x, swz16(x));
}
__device__ __forceinline__ float red32sum(float x) {
    x += dppf<0x128>(x);
    x += dppf<0x124>(x);
    x += dppf<0x122>(x);
    x += dppf<0x121>(x);
    return x + swz16(x);
}

// ---- packed bf16-pair MAC: 1 shl + 1 and + 1 v_pk_fma_f32 ----
// acc.{lo,hi} += {bf16lo(z), bf16hi(z)} * ap[SEL]
template<int SEL>
__device__ __forceinline__ void pkfma2(float2v& acc, unsigned int z, float2v ap) {
    float2v x;
    x[0] = __uint_as_float(z << 16);
    x[1] = __uint_as_float(z & 0xffff0000u);
    if (SEL == 0)
        asm("v_pk_fma_f32 %0, %1, %2, %0 op_sel:[0,0,0] op_sel_hi:[1,0,1]"
            : "+v"(acc) : "v"(x), "v"(ap));
    else
        asm("v_pk_fma_f32 %0, %1, %2, %0 op_sel:[0,1,0] op_sel_hi:[1,1,1]"
            : "+v"(acc) : "v"(x), "v"(ap));
}

// params block layout (floats)
#define P_WIH 0
#define P_WHH 3072
#define P_BIH 6144
#define P_BHH 6240
#define P_WR1 6336
#define P_BR1 6676
#define P_WR2 6686
#define P_BR2 6754
#define P_I   6756
#define P_R   6788
#define P_S   6820
#define P_IT  6852
#define P_RT  6884
#define P_N   6916
#define P_HX0 6917
#define P_TOT 6949

// round-15: multi-block grid-strided (was a serial single-block preamble)
__global__ __launch_bounds__(256) void norm_params(
    const void* W1, const void* a1, const void* W2, const void* a2,
    const void* W_ih, const void* W_hh, const void* b_ih, const void* b_hh,
    const void* Wr1, const void* br1, const void* Wr2, const void* br2,
    const void* Iv, const void* Rv, const void* Sv, const void* Itv, const void* Rtv,
    const void* Nv, const void* hx0,
    float* __restrict__ P, unsigned short* __restrict__ WbT1,
    unsigned short* __restrict__ WbT2)
{
    bool f32 = detect_f32((const unsigned short*)Nv);
    int gtid = blockIdx.x * 256 + threadIdx.x;
    int gstr = gridDim.x * 256;
    struct Item { const void* p; int n; int off; };
    const Item items[15] = {
        {W_ih, 3072, P_WIH}, {W_hh, 3072, P_WHH}, {b_ih, 96, P_BIH}, {b_hh, 96, P_BHH},
        {Wr1, 340, P_WR1}, {br1, 10, P_BR1}, {Wr2, 68, P_WR2}, {br2, 2, P_BR2},
        {Iv, 32, P_I}, {Rv, 32, P_R}, {Sv, 32, P_S}, {Itv, 32, P_IT}, {Rtv, 32, P_RT},
        {Nv, 1, P_N}, {hx0, 32, P_HX0}
    };
    for (int it = 0; it < 15; it++)
        for (int i = gtid; i < items[it].n; i += gstr)
            P[items[it].off + i] = ldf(items[it].p, i, f32);

    for (int idx = gtid; idx < 144 * 128; idx += gstr) {
        int col = idx >> 7, k = idx & 127;
        float v = 0.f;
        if (col < 128) {
            int h = col >> 5, e = col & 31;
            v = ldf(W1, (h * 128 + k) * 32 + e, f32);
        } else if (col < 136) {
            int q = col - 128;
            int h = (q < 4) ? q : q - 4;
            int off = (q < 4) ? 0 : 32;
            float s = 0.f;
            for (int e = 0; e < 32; e++)
                s += ldf(W1, (h * 128 + k) * 32 + e, f32) * ldf(a1, h * 64 + off + e, f32);
            v = s;
        }
        WbT1[col * 128 + k] = f2bf(v);
    }
    for (int idx = gtid; idx < 48 * 128; idx += gstr) {
        int col = idx >> 7, k = idx & 127;
        float v = 0.f;
        if (col < 32) {
            v = ldf(W2, k * 32 + col, f32);
        } else if (col < 34) {
            int off = (col == 32) ? 0 : 32;
            float s = 0.f;
            for (int e = 0; e < 32; e++)
                s += ldf(W2, k * 32 + e, f32) * ldf(a2, off + e, f32);
            v = s;
        }
        WbT2[col * 128 + k] = f2bf(v);
    }
}

// ---------------------------------------------------------------------------
// K1/K3: C[M x NT*16] = X[M x 128] @ WbT^T via MFMA 16x16x32 bf16.
// ---------------------------------------------------------------------------
template<int NT, int HC, bool DYN>
__global__ __launch_bounds__(256) void gat_linear(
    const void* __restrict__ Xv, const unsigned short* __restrict__ WbT,
    unsigned short* __restrict__ Z, float* __restrict__ EL, float* __restrict__ ER,
    const unsigned short* __restrict__ Nv, long row0)
{
    constexpr int NCOL = NT * 16;
    constexpr int LDW  = 136;
    __shared__ unsigned short Ws[NCOL * LDW];
    int tid = threadIdx.x;
    for (int idx = tid; idx < NCOL * 16; idx += 256) {
        int col = idx >> 4, ch = idx & 15;
        *(uint4v*)(&Ws[col * LDW + ch * 8]) = *(const uint4v*)(&WbT[col * 128 + ch * 8]);
    }
    __syncthreads();

    bool f32 = DYN ? detect_f32(Nv) : false;
    int wave = tid >> 6, lane = tid & 63;
    int l15 = lane & 15, quad = lane >> 4;
    long lrow = (long)blockIdx.x * 64 + wave * 16;

    floatx4 acc[NT];
    floatx4 zz = {0.f, 0.f, 0.f, 0.f};
    #pragma unroll
    for (int i = 0; i < NT; i++) acc[i] = zz;

    long xoff = (row0 + lrow + l15) * 128 + quad * 8;
    #pragma unroll
    for (int kt = 0; kt < 4; kt++) {
        short8 afrag;
        if (DYN && f32) {
            const float* xr = (const float*)Xv + xoff + kt * 32;
            float4 u0 = ((const float4*)xr)[0];
            float4 u1 = ((const float4*)xr)[1];
            union { short8 v; unsigned short u[8]; } af;
            af.u[0] = f2bf(u0.x); af.u[1] = f2bf(u0.y);
            af.u[2] = f2bf(u0.z); af.u[3] = f2bf(u0.w);
            af.u[4] = f2bf(u1.x); af.u[5] = f2bf(u1.y);
            af.u[6] = f2bf(u1.z); af.u[7] = f2bf(u1.w);
            afrag = af.v;
        } else {
            afrag = *(const short8*)((const unsigned short*)Xv + xoff + kt * 32);
        }
        #pragma unroll
        for (int nt = 0; nt < NT; nt++) {
            short8 bfrag = *(const short8*)(&Ws[(nt * 16 + l15) * LDW + kt * 32 + quad * 8]);
            acc[nt] = __builtin_amdgcn_mfma_f32_16x16x32_bf16(afrag, bfrag, acc[nt], 0, 0, 0);
        }
    }

    #pragma unroll
    for (int nt = 0; nt < NT; nt++) {
        int col = nt * 16 + l15;
        #pragma unroll
        for (int r = 0; r < 4; r++) {
            long grow = lrow + quad * 4 + r;
            float v = acc[nt][r];
            if (col < HC * 32) {
                Z[grow * (HC * 32) + col] = f2bf(v);
            } else if (col < HC * 32 + HC) {
                EL[grow * HC + (col - HC * 32)] = v;
            } else if (col < HC * 32 + 2 * HC) {
                ER[grow * HC + (col - HC * 32 - HC)] = v;
            }
        }
    }
}

// ---------------------------------------------------------------------------
// K2: GAT1 aggregation (round-14 structure, unchanged this round).
// ---------------------------------------------------------------------------
__device__ __forceinline__ void iss8(uint4v* buf, const int4v sa, const int4v sb,
                                     const char* Zb, unsigned fb) {
    #pragma unroll
    for (int k = 0; k < 4; k++)
        buf[k] = *(const uint4v*)(Zb + (unsigned)(sa[k] * 256) + fb);
    #pragma unroll
    for (int k = 0; k < 4; k++)
        buf[4 + k] = *(const uint4v*)(Zb + (unsigned)(sb[k] * 256) + fb);
}
__device__ __forceinline__ void cons8(const uint4v* buf, const floatx4 ax, const floatx4 ay,
                                      float2v& c0, float2v& c1, float2v& c2, float2v& c3) {
    float2v a01 = {ax[0], ax[1]};
    float2v a23 = {ax[2], ax[3]};
    float2v a45 = {ay[0], ay[1]};
    float2v a67 = {ay[2], ay[3]};
    #define STEP(K, AP, SEL)              \
        pkfma2<SEL>(c0, buf[K].x, AP);    \
        pkfma2<SEL>(c1, buf[K].y, AP);    \
        pkfma2<SEL>(c2, buf[K].z, AP);    \
        pkfma2<SEL>(c3, buf[K].w, AP);
    STEP(0, a01, 0) STEP(1, a01, 1)
    STEP(2, a23, 0) STEP(3, a23, 1)
    STEP(4, a45, 0) STEP(5, a45, 1)
    STEP(6, a67, 0) STEP(7, a67, 1)
    #undef STEP
}

__global__ __launch_bounds__(256, 5) void gat1_aggr(
    const int* __restrict__ src,
    const unsigned short* __restrict__ Z,   // (TC*10000) x 128 bf16
    const float* __restrict__ EL,           // (TC*10000) x 4
    const float* __restrict__ ER,
    unsigned short* __restrict__ H1,        // (TC*10000) x 128 bf16
    int NX)
{
    __shared__ float als[4][4][4][36];      // [wave][node][head][d(+pad4)]
    __shared__ int   sid[4][4][32];         // [wave][node][d]
    int tid = threadIdx.x;
    int w = tid >> 6, lane = tid & 63;
    int d31 = lane & 31, hf = lane >> 5;

    int bid = blockIdx.x;
    int xcd = bid % NX;
    int j   = bid / NX;
    int tq  = j / 625;
    int r   = j - tq * 625;
    int t   = tq * NX + xcd;
    int tb  = t * 10000;
    int n0  = r * 16 + w * 4;               // n0+3 <= 9999 always
    const char* Zb = (const char*)Z + (size_t)tb * 256;

    // ---- phase A: 4 softmaxes, de-duplicated gathers ----
    int sidx[4];
    #pragma unroll
    for (int jj = 0; jj < 4; jj++)
        sidx[jj] = src[(n0 + jj) * 32 + d31];

    int mA = hf ? sidx[1] : sidx[0];
    int mB = hf ? sidx[3] : sidx[2];
    floatx4 elA = *(const floatx4*)(EL + (size_t)(tb + mA) * 4);
    floatx4 elB = *(const floatx4*)(EL + (size_t)(tb + mB) * 4);
    floatx4 erA = *(const floatx4*)(ER + (size_t)(tb + n0 + hf) * 4);
    floatx4 erB = *(const floatx4*)(ER + (size_t)(tb + n0 + 2 + hf) * 4);

    float xA[4], xB[4];
    #pragma unroll
    for (int h = 0; h < 4; h++) {
        float a = elA[h] + erA[h];
        float b = elB[h] + erB[h];
        a = a >= 0.f ? a : 0.01f * a;
        b = b >= 0.f ? b : 0.01f * b;
        xA[h] = __expf(a - red32max(a));
        xB[h] = __expf(b - red32max(b));
    }
    #pragma unroll
    for (int h = 0; h < 4; h++) {
        als[w][hf][h][d31]     = xA[h] * __builtin_amdgcn_rcpf(red32sum(xA[h]));
        als[w][2 + hf][h][d31] = xB[h] * __builtin_amdgcn_rcpf(red32sum(xB[h]));
    }
    if (hf == 0) {
        #pragma unroll
        for (int jj = 0; jj < 4; jj++)
            sid[w][jj][d31] = sidx[jj];
    }
    __builtin_amdgcn_wave_barrier();

    // ---- phase B: per-lane full neighbor sum, all 4 nodes in one pass ----
    int u = lane >> 4;          // node within group of 4
    int f = lane & 15;          // dim chunk (8 dims)
    int h = f >> 2;             // head of this chunk
    unsigned fb = (unsigned)f * 16u;

    {
        int jj = u;
        const int* sp = &sid[w][jj][0];
        int4v sv0 = *(const int4v*)(sp + 0);
        int4v sv1 = *(const int4v*)(sp + 4);
        int4v sv2 = *(const int4v*)(sp + 8);
        int4v sv3 = *(const int4v*)(sp + 12);
        int4v sv4 = *(const int4v*)(sp + 16);
        int4v sv5 = *(const int4v*)(sp + 20);
        int4v sv6 = *(const int4v*)(sp + 24);
        int4v sv7 = *(const int4v*)(sp + 28);

        uint4v zA[8], zB[8];
        iss8(zA, sv0, sv1, Zb, fb);       // k 0..7 in flight
        iss8(zB, sv2, sv3, Zb, fb);       // k 8..15 in flight

        const float* ap_ = &als[w][jj][h][0];
        floatx4 av0 = *(const floatx4*)(ap_ + 0);
        floatx4 av1 = *(const floatx4*)(ap_ + 4);
        floatx4 av2 = *(const floatx4*)(ap_ + 8);
        floatx4 av3 = *(const floatx4*)(ap_ + 12);
        floatx4 av4 = *(const floatx4*)(ap_ + 16);
        floatx4 av5 = *(const floatx4*)(ap_ + 20);
        floatx4 av6 = *(const floatx4*)(ap_ + 24);
        floatx4 av7 = *(const floatx4*)(ap_ + 28);

        float2v c0 = {0.f, 0.f}, c1 = {0.f, 0.f}, c2 = {0.f, 0.f}, c3 = {0.f, 0.f};
        cons8(zA, av0, av1, c0, c1, c2, c3);
        iss8(zA, sv4, sv5, Zb, fb);       // k 16..23
        cons8(zB, av2, av3, c0, c1, c2, c3);
        iss8(zB, sv6, sv7, Zb, fb);       // k 24..31
        cons8(zA, av4, av5, c0, c1, c2, c3);
        cons8(zB, av6, av7, c0, c1, c2, c3);

        int n = n0 + jj;
        float p0 = fmaxf(c0[0], 0.f), p1 = fmaxf(c0[1], 0.f);
        float p2 = fmaxf(c1[0], 0.f), p3 = fmaxf(c1[1], 0.f);
        float p4 = fmaxf(c2[0], 0.f), p5 = fmaxf(c2[1], 0.f);
        float p6 = fmaxf(c3[0], 0.f), p7 = fmaxf(c3[1], 0.f);
        unsigned r0, r1, r2, r3;
        asm("v_cvt_pk_bf16_f32 %0, %1, %2" : "=v"(r0) : "v"(p0), "v"(p1));
        asm("v_cvt_pk_bf16_f32 %0, %1, %2" : "=v"(r1) : "v"(p2), "v"(p3));
        asm("v_cvt_pk_bf16_f32 %0, %1, %2" : "=v"(r2) : "v"(p4), "v"(p5));
        asm("v_cvt_pk_bf16_f32 %0, %1, %2" : "=v"(r3) : "v"(p6), "v"(p7));
        uint4v o = {r0, r1, r2, r3};
        __builtin_nontemporal_store(o,
            (uint4v*)((char*)H1 + (size_t)(tb + n) * 256 + fb));
    }
}

// ---------------------------------------------------------------------------
// K4: GAT2 aggregation + relu + max pool, round-15: gat1-style lane remap.
// Lane owns (node u3 = lane>>3, dims f7*4..f7*4+3); full 32-neighbor sum
// per lane with zero cross-lane ops; sid2/als2 staged in LDS (pad 36 ->
// conflict-free b128 row reads, 16B-aligned); double-buffered uint2v
// gathers (512B/instr, same coalescing as before); ONE 3-step cross-lane
// max per wave replaces 64 per-node ds_bpermute chains; no divergent
// continue (clamped duplicates are idempotent under max).
// ---------------------------------------------------------------------------
__device__ __forceinline__ void iss8b(uint2v* buf, const int4v sa, const int4v sb,
                                      const char* Zb, unsigned fb) {
    #pragma unroll
    for (int k = 0; k < 4; k++)
        buf[k] = *(const uint2v*)(Zb + (unsigned)(sa[k] * 64) + fb);
    #pragma unroll
    for (int k = 0; k < 4; k++)
        buf[4 + k] = *(const uint2v*)(Zb + (unsigned)(sb[k] * 64) + fb);
}
__device__ __forceinline__ void cons8b(const uint2v* buf, const floatx4 ax, const floatx4 ay,
                                       float2v& c01, float2v& c23) {
    float2v a01 = {ax[0], ax[1]};
    float2v a23 = {ax[2], ax[3]};
    float2v a45 = {ay[0], ay[1]};
    float2v a67 = {ay[2], ay[3]};
    pkfma2<0>(c01, buf[0].x, a01); pkfma2<0>(c23, buf[0].y, a01);
    pkfma2<1>(c01, buf[1].x, a01); pkfma2<1>(c23, buf[1].y, a01);
    pkfma2<0>(c01, buf[2].x, a23); pkfma2<0>(c23, buf[2].y, a23);
    pkfma2<1>(c01, buf[3].x, a23); pkfma2<1>(c23, buf[3].y, a23);
    pkfma2<0>(c01, buf[4].x, a45); pkfma2<0>(c23, buf[4].y, a45);
    pkfma2<1>(c01, buf[5].x, a45); pkfma2<1>(c23, buf[5].y, a45);
    pkfma2<0>(c01, buf[6].x, a67); pkfma2<0>(c23, buf[6].y, a67);
    pkfma2<1>(c01, buf[7].x, a67); pkfma2<1>(c23, buf[7].y, a67);
}

__global__ __launch_bounds__(256, 4) void gat2_aggr(
    const int* __restrict__ src,
    const unsigned short* __restrict__ Z2,  // (TC*10000) x 32 bf16
    const float* __restrict__ EL2,          // (TC*10000)
    const float* __restrict__ ER2,
    int* __restrict__ cur, int t0, int NX)
{
    __shared__ float als2[4][16][36];       // [wave][node][d(+pad)]
    __shared__ int   sid2[4][16][36];
    __shared__ int bm[32];
    int tid = threadIdx.x, w = tid >> 6, lane = tid & 63;
    int d31 = lane & 31, g = lane >> 5;
    int u3 = lane >> 3, f7 = lane & 7;

    int bid = blockIdx.x;
    int xcd = bid % NX;
    int j   = bid / NX;
    int tq  = j / 157;
    int r   = j - tq * 157;
    int t   = tq * NX + xcd;
    int tb  = t * 10000;
    int n0  = r * 64 + w * 16;
    const char* Zb = (const char*)Z2 + (size_t)tb * 64;

    if (tid < 32) bm[tid] = 0;
    __syncthreads();

    // ---- softmax for 16 nodes (de-duplicated: each half owns 2k+g) ----
    #pragma unroll
    for (int b = 0; b < 2; b++) {
        int nb = n0 + b * 8;
        float xv[4]; int sv[4];
        #pragma unroll
        for (int k = 0; k < 4; k++) {
            int n = nb + 2 * k + g;
            n = n > 9999 ? 9999 : n;
            sv[k] = src[n * 32 + d31];
            float e = EL2[tb + sv[k]] + ER2[tb + n];
            e = e >= 0.f ? e : 0.01f * e;
            xv[k] = __expf(e - red32max(e));
        }
        #pragma unroll
        for (int k = 0; k < 4; k++) {
            int slot = b * 8 + 2 * k + g;
            als2[w][slot][d31] = xv[k] * __builtin_amdgcn_rcpf(red32sum(xv[k]));
            sid2[w][slot][d31] = sv[k];
        }
    }
    __builtin_amdgcn_wave_barrier();

    // ---- aggregation: 2 passes x 8 nodes; zero cross-lane in the sum ----
    unsigned fb = (unsigned)f7 * 8u;
    float2v m01 = {0.f, 0.f}, m23 = {0.f, 0.f};
    #pragma unroll
    for (int b = 0; b < 2; b++) {
        int jj = b * 8 + u3;
        const int* sp = &sid2[w][jj][0];
        int4v sv0 = *(const int4v*)(sp + 0);
        int4v sv1 = *(const int4v*)(sp + 4);
        int4v sv2 = *(const int4v*)(sp + 8);
        int4v sv3 = *(const int4v*)(sp + 12);
        int4v sv4 = *(const int4v*)(sp + 16);
        int4v sv5 = *(const int4v*)(sp + 20);
        int4v sv6 = *(const int4v*)(sp + 24);
        int4v sv7 = *(const int4v*)(sp + 28);

        uint2v zA[8], zB[8];
        iss8b(zA, sv0, sv1, Zb, fb);      // k 0..7
        iss8b(zB, sv2, sv3, Zb, fb);      // k 8..15

        const float* ap_ = &als2[w][jj][0];
        floatx4 av0 = *(const floatx4*)(ap_ + 0);
        floatx4 av1 = *(const floatx4*)(ap_ + 4);
        floatx4 av2 = *(const floatx4*)(ap_ + 8);
        floatx4 av3 = *(const floatx4*)(ap_ + 12);
        floatx4 av4 = *(const floatx4*)(ap_ + 16);
        floatx4 av5 = *(const floatx4*)(ap_ + 20);
        floatx4 av6 = *(const floatx4*)(ap_ + 24);
        floatx4 av7 = *(const floatx4*)(ap_ + 28);

        float2v c01 = {0.f, 0.f}, c23 = {0.f, 0.f};
        cons8b(zA, av0, av1, c01, c23);
        iss8b(zA, sv4, sv5, Zb, fb);      // k 16..23
        cons8b(zB, av2, av3, c01, c23);
        iss8b(zB, sv6, sv7, Zb, fb);      // k 24..31
        cons8b(zA, av4, av5, c01, c23);
        cons8b(zB, av6, av7, c01, c23);

        m01[0] = fmaxf(m01[0], c01[0]);
        m01[1] = fmaxf(m01[1], c01[1]);
        m23[0] = fmaxf(m23[0], c23[0]);
        m23[1] = fmaxf(m23[1], c23[1]);
    }

    // ---- one cross-group max (lane bits 3,4,5), then 32 block atomics ----
    float c0 = m01[0], c1 = m01[1], c2 = m23[0], c3 = m23[1];
    c0 = fmaxf(c0, dppf<0x128>(c0)); c1 = fmaxf(c1, dppf<0x128>(c1));
    c2 = fmaxf(c2, dppf<0x128>(c2)); c3 = fmaxf(c3, dppf<0x128>(c3));
    c0 = fmaxf(c0, swz16(c0)); c1 = fmaxf(c1, swz16(c1));
    c2 = fmaxf(c2, swz16(c2)); c3 = fmaxf(c3, swz16(c3));
    c0 = fmaxf(c0, __shfl_xor(c0, 32)); c1 = fmaxf(c1, __shfl_xor(c1, 32));
    c2 = fmaxf(c2, __shfl_xor(c2, 32)); c3 = fmaxf(c3, __shfl_xor(c3, 32));
    if (lane < 8) {
        atomicMax(&bm[f7 * 4 + 0], __float_as_int(c0));
        atomicMax(&bm[f7 * 4 + 1], __float_as_int(c1));
        atomicMax(&bm[f7 * 4 + 2], __float_as_int(c2));
        atomicMax(&bm[f7 * 4 + 3], __float_as_int(c3));
    }
    __syncthreads();
    if (tid < 32) atomicMax(&cur[(t0 + t) * 32 + tid], bm[tid]);
}

// ---------------------------------------------------------------------------
// K5: GRU + readout + SIR physics. gi[t] precomputed (hx-independent).
// ---------------------------------------------------------------------------
__global__ __launch_bounds__(128) void gru_head(
    const float* __restrict__ P, const float* __restrict__ cur,
    void* __restrict__ outv, const unsigned short* __restrict__ Nv)
{
    bool f32 = detect_f32(Nv);
    __shared__ float Whh[96 * 32], giAll[32 * 96];
    __shared__ float hx[32], gh[96], nh[34];
    int tid = threadIdx.x;
    for (int i = tid; i < 96 * 32; i += 128)
        Whh[i] = P[P_WHH + i];
    for (int o = tid; o < 32 * 96; o += 128) {
        int t = o / 96, gg = o - t * 96;
        float s = P[P_BIH + gg];
        for (int k = 0; k < 32; k++)
            s += cur[t * 32 + k] * P[P_WIH + gg * 32 + k];
        giAll[o] = s;
    }
    if (tid < 32) hx[tid] = P[P_HX0 + tid];
    __syncthreads();

    for (int t = 0; t < 32; t++) {
        if (tid < 96) {
            float sh = 0.f;
            for (int k = 0; k < 32; k++)
                sh += hx[k] * Whh[tid * 32 + k];
            gh[tid] = sh + P[P_BHH + tid];
        }
        __syncthreads();
        if (tid < 32) {
            const float* gi = &giAll[t * 96];
            float r  = 1.f / (1.f + __expf(-(gi[tid] + gh[tid])));
            float zg = 1.f / (1.f + __expf(-(gi[32 + tid] + gh[32 + tid])));
            float ng = tanhf(gi[64 + tid] + r * gh[64 + tid]);
            float hv = (1.f - zg) * ng + zg * hx[tid];
            hx[tid] = hv;
            nh[tid] = hv;
            if (tid == 0) { nh[32] = P[P_IT + t]; nh[33] = P[P_RT + t]; }
        }
        __syncthreads();
        if (tid < 10) {
            float s = P[P_BR1 + tid];
            for (int k = 0; k < 34; k++) s += nh[k] * P[P_WR1 + tid * 34 + k];
            int i = tid >> 1;
            int oi = ((tid & 1) == 0) ? (t * 5 + i) : (160 + t * 5 + i);
            if (f32) ((float*)outv)[oi] = s;
            else     ((unsigned short*)outv)[oi] = f2bf(s);
        }
        if (tid == 64) {
            float ab0 = P[P_BR2 + 0], ab1 = P[P_BR2 + 1];
            for (int k = 0; k < 34; k++) {
                ab0 += nh[k] * P[P_WR2 + k];
                ab1 += nh[k] * P[P_WR2 + 34 + k];
            }
            float a_s = 1.f / (1.f + __expf(-ab0));
            float b_s = 1.f / (1.f + __expf(-ab1));
            float Ns = P[P_N];
            float lI = P[P_I + t], lR = P[P_R + t], lS = P[P_S + t];
            float dI = 0.f, dR = 0.f;
            for (int i = 0; i < 5; i++) {
                if (i > 0) { lI += dI; lR += dR; lS = Ns - lI - lR; }
                dI = a_s * lI * (lS / Ns) - b_s * lI;
                dR = b_s * lI;
                if (f32) {
                    ((float*)outv)[320 + t * 5 + i] = dI;
                    ((float*)outv)[480 + t * 5 + i] = dR;
                } else {
                    ((unsigned short*)outv)[320 + t * 5 + i] = f2bf(dI);
                    ((unsigned short*)outv)[480 + t * 5 + i] = f2bf(dR);
                }
            }
        }
        __syncthreads();
    }
}

extern "C" void kernel_launch(void* const* d_in, const int* in_sizes, int n_in,
                              void* d_out, int out_size, void* d_ws, size_t ws_size,
                              hipStream_t stream) {
    const void* h    = d_in[0];
    const int*  src  = (const int*)d_in[1];
    const void* Nv   = d_in[2];
    const void* Iv   = d_in[3];
    const void* Rv   = d_in[4];
    const void* Sv   = d_in[5];
    const void* Itv  = d_in[6];
    const void* Rtv  = d_in[7];
    const void* hx0  = d_in[8];
    const void* W1   = d_in[9];
    const void* a1   = d_in[10];
    const void* W2   = d_in[11];
    const void* a2   = d_in[12];
    const void* W_ih = d_in[13];
    const void* W_hh = d_in[14];
    const void* b_ih = d_in[15];
    const void* b_hh = d_in[16];
    const void* Wr1  = d_in[17];
    const void* br1  = d_in[18];
    const void* Wr2  = d_in[19];
    const void* br2  = d_in[20];
    const unsigned short* Nu = (const unsigned short*)Nv;

    int TC = 4;
    for (int c = 32; c >= 4; c >>= 1) {
        size_t need = (size_t)c * 10000 * (128 * 2 + 128 * 2 + 16 + 16) + (1 << 20);
        if (need <= ws_size) { TC = c; break; }
    }
    long CR = (long)TC * 10000;

    char* ws = (char*)d_ws;
    size_t off = 0;
    auto alloc = [&](size_t b) {
        void* p = ws + off;
        off += (b + 255) & ~(size_t)255;
        return p;
    };
    float*          Pb   = (float*)alloc(P_TOT * 4);
    unsigned short* WbT1 = (unsigned short*)alloc(144 * 128 * 2);
    unsigned short* WbT2 = (unsigned short*)alloc(48 * 128 * 2);
    float*          cur  = (float*)alloc(32 * 32 * 4);
    unsigned short* z1   = (unsigned short*)alloc((size_t)CR * 128 * 2);
    unsigned short* h1   = (unsigned short*)alloc((size_t)CR * 128 * 2);
    float*          el1  = (float*)alloc((size_t)CR * 4 * 4);
    float*          er1  = (float*)alloc((size_t)CR * 4 * 4);
    unsigned short* z2   = z1;
    float*          el2  = el1;
    float*          er2  = er1;

    (void)hipMemsetAsync(cur, 0, 32 * 32 * 4, stream);
    norm_params<<<48, 256, 0, stream>>>(W1, a1, W2, a2, W_ih, W_hh, b_ih, b_hh,
                                        Wr1, br1, Wr2, br2, Iv, Rv, Sv, Itv, Rtv,
                                        Nv, hx0, Pb, WbT1, WbT2);
    int nchunks = 32 / TC;
    int g1 = (int)(CR / 64);
    int NX = TC < 8 ? TC : 8;     // t-slice -> XCD interleave factor
    int TQ = TC / NX;
    for (int c = 0; c < nchunks; c++) {
        long row0 = (long)c * CR;
        gat_linear<9, 4, true><<<g1, 256, 0, stream>>>(h, WbT1, z1, el1, er1, Nu, row0);
        gat1_aggr<<<NX * 625 * TQ, 256, 0, stream>>>(src, z1, el1, er1, h1, NX);
        gat_linear<3, 1, false><<<g1, 256, 0, stream>>>(h1, WbT2, z2, el2, er2, Nu, 0);
        gat2_aggr<<<NX * 157 * TQ, 256, 0, stream>>>(src, z2, el2, er2, (int*)cur, c * TC, NX);
    }
    gru_head<<<1, 128, 0, stream>>>(Pb, cur, d_out, Nu);
}